// Round 1
// baseline (228.897 us; speedup 1.0000x reference)
//
#include <hip/hip_runtime.h>
#include <math.h>

// MoE top-2 router, fused: logits GEMM (split-bf16 MFMA, fp32-accurate) +
// softmax + top-2 + 4 outputs.
//
// x: [16384, 2048] fp32, W: [64, 2048] fp32.
// outputs (concat, fp32): mask [T,64], indices-as-float [T,2],
//                         router_probs [T,64], probs [T,64]

#define D_DIM 2048
#define E_DIM 64
#define TM 64            // tokens per block
#define KB 64            // k-chunk (2 MFMA k-steps of 32)
#define NCH (D_DIM / KB) // 32 chunks
#define LDST 72          // LDS row stride in shorts (pad 8 -> <=2-way conflicts)

typedef __bf16 bf16x8 __attribute__((ext_vector_type(8)));
typedef float f32x4 __attribute__((ext_vector_type(4)));

static __device__ __forceinline__ unsigned short f2bf(float f) {
    unsigned int u = __float_as_uint(f);
    u += 0x7fffu + ((u >> 16) & 1u);   // RNE round to bf16
    return (unsigned short)(u >> 16);
}
static __device__ __forceinline__ float bf2f(unsigned short h) {
    return __uint_as_float(((unsigned int)h) << 16);
}
// split fp32 -> hi bf16 + lo bf16 (residual); x ~= hi + lo to ~2^-18 rel
static __device__ __forceinline__ void split4(const float4 v, ushort4* h, ushort4* l) {
    h->x = f2bf(v.x); l->x = f2bf(v.x - bf2f(h->x));
    h->y = f2bf(v.y); l->y = f2bf(v.y - bf2f(h->y));
    h->z = f2bf(v.z); l->z = f2bf(v.z - bf2f(h->z));
    h->w = f2bf(v.w); l->w = f2bf(v.w - bf2f(h->w));
}

__global__ __launch_bounds__(256, 1) void router_fused(
    const float* __restrict__ x, const float* __restrict__ W,
    float* __restrict__ mask_out, float* __restrict__ idx_out,
    float* __restrict__ rp_out, float* __restrict__ probs_out)
{
    __shared__ __align__(16) unsigned short XH[TM * LDST];
    __shared__ __align__(16) unsigned short XL[TM * LDST];
    __shared__ __align__(16) unsigned short WH[E_DIM * LDST];
    __shared__ __align__(16) unsigned short WL[E_DIM * LDST];
    __shared__ float LG[TM * 65];   // logits, padded row 65

    const int tid  = threadIdx.x;
    const int lane = tid & 63;
    const int wv   = tid >> 6;       // wave 0..3 -> token rows 16*wv..16*wv+15
    const int quad = lane >> 4;
    const int l16  = lane & 15;
    const int t0   = blockIdx.x * TM;

    const float4* x4 = (const float4*)x;
    const float4* w4 = (const float4*)W;

    // staging map: thread loads (r0+16i, c4) float4 of the 64x64 fp32 tile
    const int r0 = tid >> 4;   // 0..15
    const int c4 = tid & 15;   // float4 column 0..15

    f32x4 acc[4];
    #pragma unroll
    for (int n = 0; n < 4; ++n) { f32x4 z = {0.f, 0.f, 0.f, 0.f}; acc[n] = z; }

    // prefetch chunk 0 into registers
    float4 xr[4], wr[4];
    #pragma unroll
    for (int i = 0; i < 4; ++i) {
        int row = r0 + 16 * i;
        xr[i] = x4[(t0 + row) * 512 + c4];
        wr[i] = w4[row * 512 + c4];
    }

    for (int ch = 0; ch < NCH; ++ch) {
        // convert fp32 -> bf16 hi/lo, store to LDS
        #pragma unroll
        for (int i = 0; i < 4; ++i) {
            int row = r0 + 16 * i;
            ushort4 h, l;
            split4(xr[i], &h, &l);
            *(ushort4*)&XH[row * LDST + c4 * 4] = h;
            *(ushort4*)&XL[row * LDST + c4 * 4] = l;
            split4(wr[i], &h, &l);
            *(ushort4*)&WH[row * LDST + c4 * 4] = h;
            *(ushort4*)&WL[row * LDST + c4 * 4] = l;
        }
        __syncthreads();

        // register-prefetch next chunk (overlaps MFMA below)
        if (ch + 1 < NCH) {
            #pragma unroll
            for (int i = 0; i < 4; ++i) {
                int row = r0 + 16 * i;
                xr[i] = x4[(t0 + row) * 512 + (ch + 1) * 16 + c4];
                wr[i] = w4[row * 512 + (ch + 1) * 16 + c4];
            }
        }

        // 2 k-steps of 32; 3-term split-bf16 MFMA (xh*wh + xl*wh + xh*wl)
        #pragma unroll
        for (int ks = 0; ks < 2; ++ks) {
            const int kofs = ks * 32 + quad * 8;
            bf16x8 ah = *(const bf16x8*)&XH[(16 * wv + l16) * LDST + kofs];
            bf16x8 al = *(const bf16x8*)&XL[(16 * wv + l16) * LDST + kofs];
            #pragma unroll
            for (int n = 0; n < 4; ++n) {
                bf16x8 bh = *(const bf16x8*)&WH[(16 * n + l16) * LDST + kofs];
                bf16x8 bl = *(const bf16x8*)&WL[(16 * n + l16) * LDST + kofs];
                acc[n] = __builtin_amdgcn_mfma_f32_16x16x32_bf16(ah, bh, acc[n], 0, 0, 0);
                acc[n] = __builtin_amdgcn_mfma_f32_16x16x32_bf16(al, bh, acc[n], 0, 0, 0);
                acc[n] = __builtin_amdgcn_mfma_f32_16x16x32_bf16(ah, bl, acc[n], 0, 0, 0);
            }
        }
        __syncthreads();
    }

    // ---- epilogue: logits -> LDS (wave-local rows; no block sync needed) ----
    // C/D layout: col(expert) = lane&15, row(token) = quad*4 + reg   [m89/m91]
    #pragma unroll
    for (int n = 0; n < 4; ++n) {
        #pragma unroll
        for (int r = 0; r < 4; ++r) {
            int tl = 16 * wv + quad * 4 + r;
            int e  = 16 * n + l16;
            LG[tl * 65 + e] = acc[n][r];
        }
    }

    // wave handles its own 16 tokens: lane = expert
    for (int i = 0; i < 16; ++i) {
        int tl = 16 * wv + i;
        float v = LG[tl * 65 + lane];

        // argmax with lower-index tie-break (matches jax.lax.top_k) + max value
        float bv = v; int bi = lane;
        #pragma unroll
        for (int off = 1; off < 64; off <<= 1) {
            float ov = __shfl_xor(bv, off, 64);
            int   oi = __shfl_xor(bi, off, 64);
            bool take = (ov > bv) || (ov == bv && oi < bi);
            bv = take ? ov : bv;
            bi = take ? oi : bi;
        }
        float m = bv; int i1 = bi;

        // softmax
        float p = __expf(v - m);
        float s = p;
        #pragma unroll
        for (int off = 1; off < 64; off <<= 1) s += __shfl_xor(s, off, 64);
        float prob = p / s;

        // second argmax
        float v2 = (lane == i1) ? -INFINITY : v;
        float bv2 = v2; int bi2 = lane;
        #pragma unroll
        for (int off = 1; off < 64; off <<= 1) {
            float ov = __shfl_xor(bv2, off, 64);
            int   oi = __shfl_xor(bi2, off, 64);
            bool take = (ov > bv2) || (ov == bv2 && oi < bi2);
            bv2 = take ? ov : bv2;
            bi2 = take ? oi : bi2;
        }
        int i2 = bi2;

        float pd = __shfl(prob, i1, 64) + __shfl(prob, i2, 64);
        int t = t0 + tl;
        bool top = (lane == i1) || (lane == i2);

        mask_out[t * 64 + lane]  = top ? 1.f : 0.f;
        rp_out[t * 64 + lane]    = top ? prob / pd : 0.f;
        probs_out[t * 64 + lane] = prob;
        if (lane == 0) {
            idx_out[t * 2]     = (float)i1;
            idx_out[t * 2 + 1] = (float)i2;
        }
    }
}

extern "C" void kernel_launch(void* const* d_in, const int* in_sizes, int n_in,
                              void* d_out, int out_size, void* d_ws, size_t ws_size,
                              hipStream_t stream) {
    const float* x = (const float*)d_in[0];
    const float* W = (const float*)d_in[1];
    float* out = (float*)d_out;

    const int T = in_sizes[0] / D_DIM;      // 16384 tokens
    float* mask_out  = out;
    float* idx_out   = out + (size_t)T * E_DIM;
    float* rp_out    = idx_out + (size_t)T * 2;
    float* probs_out = rp_out + (size_t)T * E_DIM;

    router_fused<<<dim3(T / TM), dim3(256), 0, stream>>>(
        x, W, mask_out, idx_out, rp_out, probs_out);
}